// Round 1
// baseline (1469.302 us; speedup 1.0000x reference)
//
#include <hip/hip_runtime.h>

// Problem constants (fixed by the reference):
constexpr int Bb = 64;     // batch
constexpr int Nn = 2048;   // nodes
constexpr int CI = 64;     // in channels
constexpr int CO = 64;     // out channels
constexpr int KK = 3;      // cheb order
constexpr int DE = 10;     // embedding dim
constexpr int NW = Bb * CI;        // 4096 = columns of transposed activations
constexpr int WPSZ = KK * CI * CO; // 12288 per embedding dim

// ---------------------------------------------------------------------------
// K1: S[n, m] = softmax_m( relu( E[n]·E[m] ) )   one block per row n
// ---------------------------------------------------------------------------
__global__ __launch_bounds__(256) void supports_kernel(
    const float* __restrict__ E, float* __restrict__ S) {
  const int n = blockIdx.x;
  const int t = threadIdx.x;
  __shared__ float red[256];

  float e[DE];
#pragma unroll
  for (int d = 0; d < DE; d++) e[d] = E[n * DE + d];

  float v[8];
  float lmax = -1e30f;
#pragma unroll
  for (int j = 0; j < 8; j++) {
    const int m = t + j * 256;
    float dot = 0.f;
#pragma unroll
    for (int d = 0; d < DE; d++) dot += e[d] * E[m * DE + d];
    float r = fmaxf(dot, 0.f);
    v[j] = r;
    lmax = fmaxf(lmax, r);
  }
  red[t] = lmax;
  __syncthreads();
  for (int s = 128; s > 0; s >>= 1) {
    if (t < s) red[t] = fmaxf(red[t], red[t + s]);
    __syncthreads();
  }
  const float rowmax = red[0];
  __syncthreads();

  float lsum = 0.f;
#pragma unroll
  for (int j = 0; j < 8; j++) {
    v[j] = __expf(v[j] - rowmax);
    lsum += v[j];
  }
  red[t] = lsum;
  __syncthreads();
  for (int s = 128; s > 0; s >>= 1) {
    if (t < s) red[t] += red[t + s];
    __syncthreads();
  }
  const float inv = 1.f / red[0];
#pragma unroll
  for (int j = 0; j < 8; j++) S[n * Nn + t + j * 256] = v[j] * inv;
}

// ---------------------------------------------------------------------------
// K2: Xt[n, b*64+i] = x[b, n, i]   (float4 per thread)
// ---------------------------------------------------------------------------
__global__ __launch_bounds__(256) void transpose_kernel(
    const float* __restrict__ x, float* __restrict__ Xt) {
  const int t = blockIdx.x * 256 + threadIdx.x;  // 2,097,152 threads
  const int i = (t & 15) * 4;
  const int b = (t >> 4) & 63;
  const int n = t >> 10;
  const float4 v = *(const float4*)(x + (size_t)b * (Nn * CI) + n * CI + i);
  *(float4*)(Xt + (size_t)n * NW + b * CI + i) = v;
}

// ---------------------------------------------------------------------------
// K3: C = A @ Bm   (M=2048, K=2048, N=4096), fp32 LDS-tiled.
//     mode 1: C = 2*(A@Bm) - X2   (Chebyshev recurrence epilogue)
// 64x64 block tile, 16x16 threads, 4x4 micro-tile, K-step 16.
// ---------------------------------------------------------------------------
__global__ __launch_bounds__(256) void gemm_kernel(
    const float* __restrict__ A, const float* __restrict__ Bm,
    const float* __restrict__ X2, float* __restrict__ C, int mode) {
  constexpr int Kdim = Nn;  // 2048
  __shared__ float As[64 * 17];  // [row 0..63][k 0..15], pitch 17
  __shared__ float Bs[16 * 65];  // [k 0..15][col 0..63], pitch 65

  const int t = threadIdx.x;
  const int tx = t & 15;   // col group
  const int ty = t >> 4;   // row group
  const int n0 = blockIdx.x * 64;
  const int m0 = blockIdx.y * 64;

  // staging coords
  const int arow = t >> 2;          // 0..63
  const int acol = (t & 3) * 4;     // 0..12
  const int brow = t >> 4;          // 0..15
  const int bcol = (t & 15) * 4;    // 0..60

  float acc[4][4];
#pragma unroll
  for (int i = 0; i < 4; i++)
#pragma unroll
    for (int j = 0; j < 4; j++) acc[i][j] = 0.f;

  for (int k0 = 0; k0 < Kdim; k0 += 16) {
    float4 av = *(const float4*)(A + (size_t)(m0 + arow) * Kdim + k0 + acol);
    float4 bv = *(const float4*)(Bm + (size_t)(k0 + brow) * NW + n0 + bcol);
    __syncthreads();
    As[arow * 17 + acol + 0] = av.x;
    As[arow * 17 + acol + 1] = av.y;
    As[arow * 17 + acol + 2] = av.z;
    As[arow * 17 + acol + 3] = av.w;
    Bs[brow * 65 + bcol + 0] = bv.x;
    Bs[brow * 65 + bcol + 1] = bv.y;
    Bs[brow * 65 + bcol + 2] = bv.z;
    Bs[brow * 65 + bcol + 3] = bv.w;
    __syncthreads();
#pragma unroll
    for (int kk = 0; kk < 16; kk++) {
      float a[4], b[4];
#pragma unroll
      for (int i = 0; i < 4; i++) a[i] = As[(ty * 4 + i) * 17 + kk];
#pragma unroll
      for (int j = 0; j < 4; j++) b[j] = Bs[kk * 65 + tx * 4 + j];
#pragma unroll
      for (int i = 0; i < 4; i++)
#pragma unroll
        for (int j = 0; j < 4; j++) acc[i][j] += a[i] * b[j];
    }
  }

#pragma unroll
  for (int i = 0; i < 4; i++) {
    const size_t idx = (size_t)(m0 + ty * 4 + i) * NW + n0 + tx * 4;
    float4 o;
    if (mode == 1) {
      const float4 x2 = *(const float4*)(X2 + idx);
      o.x = 2.f * acc[i][0] - x2.x;
      o.y = 2.f * acc[i][1] - x2.y;
      o.z = 2.f * acc[i][2] - x2.z;
      o.w = 2.f * acc[i][3] - x2.w;
    } else {
      o.x = acc[i][0]; o.y = acc[i][1]; o.z = acc[i][2]; o.w = acc[i][3];
    }
    *(float4*)(C + idx) = o;
  }
}

// ---------------------------------------------------------------------------
// K4: per-node epilogue. One block per node n.
//   W_n[k,i,o] = sum_d E[n,d] * Wp[d,k,i,o]      (into LDS)
//   bias_n[o]  = sum_d E[n,d] * bp[d,o]
//   out[b,n,o] = bias_n[o] + sum_k sum_i A_k[b,i] * W_n[k,i,o]
// where A_0 = Xt[n], A_1 = XG1[n], A_2 = XG2[n]  (each contiguous [64b x 64i])
// ---------------------------------------------------------------------------
__global__ __launch_bounds__(256) void out_kernel(
    const float* __restrict__ Xt, const float* __restrict__ XG1,
    const float* __restrict__ XG2, const float* __restrict__ E,
    const float* __restrict__ Wp, const float* __restrict__ bp,
    float* __restrict__ out) {
  const int n = blockIdx.x;
  const int t = threadIdx.x;

  __shared__ float Wl[WPSZ];       // 48 KB: [k][i][o]
  __shared__ float Al[64 * 65];    // [b][i], pitch 65
  __shared__ float biasl[CO];

  float e[DE];
#pragma unroll
  for (int d = 0; d < DE; d++) e[d] = E[n * DE + d];

  // generate per-node weights
#pragma unroll
  for (int j = 0; j < WPSZ / 256; j++) {
    const int idx = t + 256 * j;
    float w = 0.f;
#pragma unroll
    for (int d = 0; d < DE; d++) w += e[d] * Wp[d * WPSZ + idx];
    Wl[idx] = w;
  }
  if (t < CO) {
    float bsum = 0.f;
#pragma unroll
    for (int d = 0; d < DE; d++) bsum += e[d] * bp[d * CO + t];
    biasl[t] = bsum;
  }

  const float* Asrc[KK] = {Xt + (size_t)n * NW, XG1 + (size_t)n * NW,
                           XG2 + (size_t)n * NW};

  const int o4 = t & 15;   // output col group: o = o4*4 + jo
  const int b4 = t >> 4;   // batch row group: b = b4*4 + jb

  float acc[4][4];
#pragma unroll
  for (int jb = 0; jb < 4; jb++)
#pragma unroll
    for (int jo = 0; jo < 4; jo++) acc[jb][jo] = 0.f;

  for (int k = 0; k < KK; k++) {
    __syncthreads();  // protect Al from previous phase readers
#pragma unroll
    for (int j = 0; j < 4; j++) {
      const int g = t * 4 + j * 1024;
      const float4 v = *(const float4*)(Asrc[k] + g);
      const int b = g >> 6, i = g & 63;
      float* dst = &Al[b * 65 + i];
      dst[0] = v.x; dst[1] = v.y; dst[2] = v.z; dst[3] = v.w;
    }
    __syncthreads();
    const float* Wk = &Wl[k * CI * CO];
#pragma unroll 16
    for (int i = 0; i < CI; i++) {
      const float4 wv = *(const float4*)(Wk + i * CO + o4 * 4);
      float av[4];
#pragma unroll
      for (int jb = 0; jb < 4; jb++) av[jb] = Al[(b4 * 4 + jb) * 65 + i];
#pragma unroll
      for (int jb = 0; jb < 4; jb++) {
        acc[jb][0] += av[jb] * wv.x;
        acc[jb][1] += av[jb] * wv.y;
        acc[jb][2] += av[jb] * wv.z;
        acc[jb][3] += av[jb] * wv.w;
      }
    }
  }

#pragma unroll
  for (int jb = 0; jb < 4; jb++) {
    const int b = b4 * 4 + jb;
    const int o = o4 * 4;
    float4 ov;
    ov.x = acc[jb][0] + biasl[o + 0];
    ov.y = acc[jb][1] + biasl[o + 1];
    ov.z = acc[jb][2] + biasl[o + 2];
    ov.w = acc[jb][3] + biasl[o + 3];
    *(float4*)(out + (size_t)b * (Nn * CO) + n * CO + o) = ov;
  }
}

// ---------------------------------------------------------------------------
extern "C" void kernel_launch(void* const* d_in, const int* in_sizes, int n_in,
                              void* d_out, int out_size, void* d_ws,
                              size_t ws_size, hipStream_t stream) {
  const float* x  = (const float*)d_in[0];   // [B,N,CI]
  const float* E  = (const float*)d_in[1];   // [N,DE]
  const float* Wp = (const float*)d_in[2];   // [DE,K,CI,CO]
  const float* bp = (const float*)d_in[3];   // [DE,CO]
  float* out = (float*)d_out;                // [B,N,CO]

  float* S   = (float*)d_ws;                      // N*N        = 4,194,304 f
  float* Xt  = S + (size_t)Nn * Nn;               // N*NW       = 8,388,608 f
  float* XG1 = Xt + (size_t)Nn * NW;              // N*NW
  float* XG2 = XG1 + (size_t)Nn * NW;             // N*NW  (total ~117 MB)

  supports_kernel<<<Nn, 256, 0, stream>>>(E, S);
  transpose_kernel<<<(Nn * NW / 4) / 256, 256, 0, stream>>>(x, Xt);

  dim3 g(NW / 64, Nn / 64);
  gemm_kernel<<<g, 256, 0, stream>>>(S, Xt, nullptr, XG1, 0);   // XG1 = S@Xt
  gemm_kernel<<<g, 256, 0, stream>>>(S, XG1, Xt, XG2, 1);       // XG2 = 2*S@XG1 - Xt

  out_kernel<<<Nn, 256, 0, stream>>>(Xt, XG1, XG2, E, Wp, bp, out);
}

// Round 3
// 279.021 us; speedup vs baseline: 5.2659x; 5.2659x over previous
//
#include <hip/hip_runtime.h>

typedef __attribute__((ext_vector_type(8))) short short8;
typedef __attribute__((ext_vector_type(4))) float f32x4;
typedef __attribute__((ext_vector_type(4))) unsigned short us4;
typedef __attribute__((ext_vector_type(8))) unsigned short us8;

constexpr int Bb = 64, Nn = 2048, CI = 64, CO = 64, KK = 3, DE = 10;
constexpr int NW = Bb * CI;          // 4096
constexpr int WPSZ = KK * CI * CO;   // 12288

__device__ __forceinline__ unsigned short f2bf(float f) {
  unsigned u = __float_as_uint(f);
  u += 0x7fff + ((u >> 16) & 1);   // RNE
  return (unsigned short)(u >> 16);
}
__device__ __forceinline__ float bf2f(unsigned short h) {
  return __uint_as_float(((unsigned)h) << 16);
}
__device__ __forceinline__ void gl2lds16(const void* g, void* l) {
  __builtin_amdgcn_global_load_lds(
      (const __attribute__((address_space(1))) void*)g,
      (__attribute__((address_space(3))) void*)l, 16, 0, 0);
}

// ---------------------------------------------------------------------------
// K1: S[n,m] = softmax_m(relu(E[n]·E[m]))  -> bf16
// ---------------------------------------------------------------------------
__global__ __launch_bounds__(256) void supports_kernel(
    const float* __restrict__ E, unsigned short* __restrict__ S) {
  const int n = blockIdx.x, t = threadIdx.x;
  __shared__ float red[256];
  float emb[DE];
#pragma unroll
  for (int d = 0; d < DE; d++) emb[d] = E[n * DE + d];
  float v[8], lmax = -1e30f;
#pragma unroll
  for (int j = 0; j < 8; j++) {
    const int m = t + j * 256;
    float dot = 0.f;
#pragma unroll
    for (int d = 0; d < DE; d++) dot += emb[d] * E[m * DE + d];
    v[j] = fmaxf(dot, 0.f);
    lmax = fmaxf(lmax, v[j]);
  }
  red[t] = lmax;
  __syncthreads();
  for (int s = 128; s > 0; s >>= 1) {
    if (t < s) red[t] = fmaxf(red[t], red[t + s]);
    __syncthreads();
  }
  const float rowmax = red[0];
  __syncthreads();
  float lsum = 0.f;
#pragma unroll
  for (int j = 0; j < 8; j++) { v[j] = __expf(v[j] - rowmax); lsum += v[j]; }
  red[t] = lsum;
  __syncthreads();
  for (int s = 128; s > 0; s >>= 1) {
    if (t < s) red[t] += red[t + s];
    __syncthreads();
  }
  const float inv = 1.f / red[0];
#pragma unroll
  for (int j = 0; j < 8; j++) S[(size_t)n * Nn + t + j * 256] = f2bf(v[j] * inv);
}

// ---------------------------------------------------------------------------
// K2: x[b,n,i] -> Xrow[n][w=b*64+i] (bf16) and XT[w][n] (bf16)
// one block per (b, 64-node tile). 64x64 floats = 4 passes of 256xfloat4.
// ---------------------------------------------------------------------------
__global__ __launch_bounds__(256) void x2xt_kernel(
    const float* __restrict__ x, unsigned short* __restrict__ Xrow,
    unsigned short* __restrict__ XT) {
  __shared__ float T[64 * 65];
  const int b = blockIdx.x, n0 = blockIdx.y * 64, t = threadIdx.x;
  const int i4 = (t & 15) * 4;
#pragma unroll
  for (int j = 0; j < 4; j++) {            // R2 bugfix: was 1 pass (16 rows)
    const int r = j * 16 + (t >> 4);       // 0..63
    const float4 v =
        *(const float4*)(x + (size_t)b * (Nn * CI) + (size_t)(n0 + r) * CI + i4);
    us4 o; o.x = f2bf(v.x); o.y = f2bf(v.y); o.z = f2bf(v.z); o.w = f2bf(v.w);
    *(us4*)(Xrow + (size_t)(n0 + r) * NW + b * CI + i4) = o;
    T[r * 65 + i4 + 0] = v.x; T[r * 65 + i4 + 1] = v.y;
    T[r * 65 + i4 + 2] = v.z; T[r * 65 + i4 + 3] = v.w;
  }
  __syncthreads();
  const int i = t >> 2, c0 = (t & 3) * 16;
  us8 p0, p1;
#pragma unroll
  for (int j = 0; j < 8; j++) p0[j] = f2bf(T[(c0 + j) * 65 + i]);
#pragma unroll
  for (int j = 0; j < 8; j++) p1[j] = f2bf(T[(c0 + 8 + j) * 65 + i]);
  unsigned short* dst = XT + (size_t)(b * CI + i) * Nn + n0 + c0;
  *(us8*)(dst) = p0;
  *(us8*)(dst + 8) = p1;
}

// ---------------------------------------------------------------------------
// K3: MFMA GEMM  C[m][w] = sum_k A[m][k] * Bt[w][k]
//   A  = S bf16 [2048][2048] (row-major, k-contig)
//   Bt = transposed B operand bf16 [4096][2048] (w-major, k-contig)
// mode 0: Crow = C,  Ct[w][m] = C (both bf16)
// mode 1: Crow = 2*C - Xsub (bf16), no Ct
// 128x128 tile, 4 waves (2x2 of 64x64), BK=64, global_load_lds w=16,
// XOR chunk swizzle in LDS (2-way max = free).
// ---------------------------------------------------------------------------
__global__ __launch_bounds__(256) void mfma_gemm(
    const unsigned short* __restrict__ A, const unsigned short* __restrict__ Bt,
    const unsigned short* __restrict__ Xsub, unsigned short* __restrict__ Crow,
    unsigned short* __restrict__ Ct, int mode) {
  __shared__ unsigned short sm[16384];  // 32 KB: As [0,8192), Bs [8192,16384)
  unsigned short* As = sm;
  unsigned short* Bs = sm + 8192;
  const int t = threadIdx.x, lane = t & 63, wave = t >> 6;
  const int n0 = blockIdx.x * 128, m0 = blockIdx.y * 128;
  const int wm = (wave & 1) * 64, wn = (wave >> 1) * 64;
  const int lr = lane & 15, lq = lane >> 4;

  f32x4 acc[4][4] = {};

  // staging: 8 rows x 8 chunks(16B) per issue; LDS slot s of row r holds
  // global chunk s ^ (r&7)
  const int srow = lane >> 3;
  const int schunk = (lane & 7) ^ srow;

  for (int k0 = 0; k0 < 2048; k0 += 64) {
    __syncthreads();
#pragma unroll
    for (int j = 0; j < 4; j++) {
      const int r0 = (wave * 4 + j) * 8;
      gl2lds16(A  + (size_t)(m0 + r0 + srow) * 2048 + k0 + schunk * 8, As + r0 * 64);
      gl2lds16(Bt + (size_t)(n0 + r0 + srow) * 2048 + k0 + schunk * 8, Bs + r0 * 64);
    }
    __syncthreads();
#pragma unroll
    for (int ks = 0; ks < 2; ks++) {
      short8 af[4], bfr[4];
#pragma unroll
      for (int i = 0; i < 4; i++) {
        const int m = wm + i * 16 + lr;
        const int slot = (ks * 4 + lq) ^ (m & 7);
        af[i] = *(const short8*)(As + m * 64 + slot * 8);
      }
#pragma unroll
      for (int j = 0; j < 4; j++) {
        const int n = wn + j * 16 + lr;
        const int slot = (ks * 4 + lq) ^ (n & 7);
        bfr[j] = *(const short8*)(Bs + n * 64 + slot * 8);
      }
#pragma unroll
      for (int i = 0; i < 4; i++)
#pragma unroll
        for (int j = 0; j < 4; j++)
          acc[i][j] = __builtin_amdgcn_mfma_f32_16x16x32_bf16(af[i], bfr[j], acc[i][j], 0, 0, 0);
    }
  }

  // ---- epilogue: frags -> swizzled LDS bf16 [128 m][128 n] ----
  // element (m,n) at us-offset m*128 + slot*8 + (n&7),
  // slot = (n>>3) ^ (m&7) ^ ((m>>3)&7)
  __syncthreads();
#pragma unroll
  for (int i = 0; i < 4; i++) {
#pragma unroll
    for (int r = 0; r < 4; r++) {
      const int m = wm + i * 16 + lq * 4 + r;
      const int sw = (m & 7) ^ ((m >> 3) & 7);
#pragma unroll
      for (int j = 0; j < 4; j++) {
        const int n = wn + j * 16 + lr;
        sm[m * 128 + (((n >> 3) ^ sw) * 8) + (n & 7)] = f2bf(acc[i][j][r]);
      }
    }
  }
  __syncthreads();

  // row-major write (+ Chebyshev fused epilogue in mode 1)
  {
    const int rr = t >> 4, cc = (t & 15) * 8;
#pragma unroll
    for (int p = 0; p < 8; p++) {
      const int m = p * 16 + rr;
      const int slot = (cc >> 3) ^ (m & 7) ^ ((m >> 3) & 7);
      us8 v = *(const us8*)(sm + m * 128 + slot * 8);
      if (mode == 1) {
        const us8 xv = *(const us8*)(Xsub + (size_t)(m0 + m) * NW + n0 + cc);
#pragma unroll
        for (int q = 0; q < 8; q++) v[q] = f2bf(2.f * bf2f(v[q]) - bf2f(xv[q]));
      }
      *(us8*)(Crow + (size_t)(m0 + m) * NW + n0 + cc) = v;
    }
  }
  // transposed write (mode 0 only): Ct[w][m]
  if (mode == 0) {
    const int w = t >> 4, mc = (t & 15) * 8;
#pragma unroll
    for (int p = 0; p < 8; p++) {
      const int n = p * 16 + w;
      us8 v;
#pragma unroll
      for (int q = 0; q < 8; q++) {
        const int m = mc + q;
        v[q] = sm[m * 128 + (((n >> 3) ^ (m & 7) ^ ((m >> 3) & 7)) * 8) + (n & 7)];
      }
      *(us8*)(Ct + (size_t)(n0 + n) * 2048 + m0 + mc) = v;
    }
  }
}

// ---------------------------------------------------------------------------
// K4: per-node output projection (fp32 math, bf16 activations)
// ---------------------------------------------------------------------------
__global__ __launch_bounds__(256) void out_kernel(
    const unsigned short* __restrict__ Xrow, const unsigned short* __restrict__ XG1,
    const unsigned short* __restrict__ XG2, const float* __restrict__ E,
    const float* __restrict__ Wp, const float* __restrict__ bp,
    float* __restrict__ out) {
  const int n = blockIdx.x, t = threadIdx.x;
  __shared__ float Wl[WPSZ];
  __shared__ float Al[64 * 65];
  __shared__ float biasl[CO];

  float emb[DE];
#pragma unroll
  for (int d = 0; d < DE; d++) emb[d] = E[n * DE + d];

#pragma unroll
  for (int j = 0; j < WPSZ / 256; j++) {
    const int idx = t + 256 * j;
    float w = 0.f;
#pragma unroll
    for (int d = 0; d < DE; d++) w += emb[d] * Wp[(size_t)d * WPSZ + idx];
    Wl[idx] = w;
  }
  if (t < CO) {
    float bsum = 0.f;
#pragma unroll
    for (int d = 0; d < DE; d++) bsum += emb[d] * bp[d * CO + t];
    biasl[t] = bsum;
  }

  const unsigned short* Asrc[KK] = {Xrow + (size_t)n * NW, XG1 + (size_t)n * NW,
                                    XG2 + (size_t)n * NW};
  const int o4 = t & 15, b4 = t >> 4;
  float acc[4][4] = {};

  for (int k = 0; k < KK; k++) {
    __syncthreads();
#pragma unroll
    for (int j = 0; j < 2; j++) {
      const int g = t * 8 + j * 2048;
      const us8 raw = *(const us8*)(Asrc[k] + g);
      const int b = g >> 6, i = g & 63;
#pragma unroll
      for (int q = 0; q < 8; q++) Al[b * 65 + i + q] = bf2f(raw[q]);
    }
    __syncthreads();
    const float* Wk = &Wl[k * CI * CO];
#pragma unroll 16
    for (int i = 0; i < CI; i++) {
      const float4 wv = *(const float4*)(Wk + i * CO + o4 * 4);
      float av[4];
#pragma unroll
      for (int jb = 0; jb < 4; jb++) av[jb] = Al[(b4 * 4 + jb) * 65 + i];
#pragma unroll
      for (int jb = 0; jb < 4; jb++) {
        acc[jb][0] += av[jb] * wv.x;
        acc[jb][1] += av[jb] * wv.y;
        acc[jb][2] += av[jb] * wv.z;
        acc[jb][3] += av[jb] * wv.w;
      }
    }
  }

#pragma unroll
  for (int jb = 0; jb < 4; jb++) {
    const int b = b4 * 4 + jb, o = o4 * 4;
    float4 ov;
    ov.x = acc[jb][0] + biasl[o + 0];
    ov.y = acc[jb][1] + biasl[o + 1];
    ov.z = acc[jb][2] + biasl[o + 2];
    ov.w = acc[jb][3] + biasl[o + 3];
    *(float4*)(out + (size_t)b * (Nn * CO) + (size_t)n * CO + o) = ov;
  }
}

// ---------------------------------------------------------------------------
extern "C" void kernel_launch(void* const* d_in, const int* in_sizes, int n_in,
                              void* d_out, int out_size, void* d_ws,
                              size_t ws_size, hipStream_t stream) {
  const float* x  = (const float*)d_in[0];
  const float* E  = (const float*)d_in[1];
  const float* Wp = (const float*)d_in[2];
  const float* bp = (const float*)d_in[3];
  float* out = (float*)d_out;

  unsigned short* S    = (unsigned short*)d_ws;          // [2048][2048]
  unsigned short* XT   = S    + (size_t)Nn * Nn;         // [4096][2048]
  unsigned short* Xrow = XT   + (size_t)NW * Nn;         // [2048][4096]
  unsigned short* XG1T = Xrow + (size_t)Nn * NW;         // [4096][2048]
  unsigned short* XG1r = XG1T + (size_t)NW * Nn;         // [2048][4096]
  unsigned short* XG2r = XG1r + (size_t)Nn * NW;         // [2048][4096]  total 88 MB

  supports_kernel<<<Nn, 256, 0, stream>>>(E, S);
  x2xt_kernel<<<dim3(Bb, Nn / 64), 256, 0, stream>>>(x, Xrow, XT);

  dim3 g(NW / 128, Nn / 128);  // (32, 16)
  mfma_gemm<<<g, 256, 0, stream>>>(S, XT,   nullptr, XG1r, XG1T, 0);
  mfma_gemm<<<g, 256, 0, stream>>>(S, XG1T, Xrow,    XG2r, nullptr, 1);

  out_kernel<<<Nn, 256, 0, stream>>>(Xrow, XG1r, XG2r, E, Wp, bp, out);
}

// Round 4
// 236.189 us; speedup vs baseline: 6.2209x; 1.1813x over previous
//
#include <hip/hip_runtime.h>

typedef __attribute__((ext_vector_type(8))) short short8;
typedef __attribute__((ext_vector_type(4))) float f32x4;
typedef __attribute__((ext_vector_type(4))) unsigned short us4;
typedef __attribute__((ext_vector_type(8))) unsigned short us8;

constexpr int Bb = 64, Nn = 2048, CI = 64, CO = 64, KK = 3, DE = 10;
constexpr int NW = Bb * CI;          // 4096
constexpr int WPSZ = KK * CI * CO;   // 12288

__device__ __forceinline__ unsigned short f2bf(float f) {
  unsigned u = __float_as_uint(f);
  u += 0x7fff + ((u >> 16) & 1);   // RNE
  return (unsigned short)(u >> 16);
}
__device__ __forceinline__ float bf2f(unsigned short h) {
  return __uint_as_float(((unsigned)h) << 16);
}
__device__ __forceinline__ void gl2lds16(const void* g, void* l) {
  __builtin_amdgcn_global_load_lds(
      (const __attribute__((address_space(1))) void*)g,
      (__attribute__((address_space(3))) void*)l, 16, 0, 0);
}

// ---------------------------------------------------------------------------
// K1: S[n,m] = softmax_m(relu(E[n]·E[m]))  -> bf16
// ---------------------------------------------------------------------------
__global__ __launch_bounds__(256) void supports_kernel(
    const float* __restrict__ E, unsigned short* __restrict__ S) {
  const int n = blockIdx.x, t = threadIdx.x;
  __shared__ float red[256];
  float emb[DE];
#pragma unroll
  for (int d = 0; d < DE; d++) emb[d] = E[n * DE + d];
  float v[8], lmax = -1e30f;
#pragma unroll
  for (int j = 0; j < 8; j++) {
    const int m = t + j * 256;
    float dot = 0.f;
#pragma unroll
    for (int d = 0; d < DE; d++) dot += emb[d] * E[m * DE + d];
    v[j] = fmaxf(dot, 0.f);
    lmax = fmaxf(lmax, v[j]);
  }
  red[t] = lmax;
  __syncthreads();
  for (int s = 128; s > 0; s >>= 1) {
    if (t < s) red[t] = fmaxf(red[t], red[t + s]);
    __syncthreads();
  }
  const float rowmax = red[0];
  __syncthreads();
  float lsum = 0.f;
#pragma unroll
  for (int j = 0; j < 8; j++) { v[j] = __expf(v[j] - rowmax); lsum += v[j]; }
  red[t] = lsum;
  __syncthreads();
  for (int s = 128; s > 0; s >>= 1) {
    if (t < s) red[t] += red[t + s];
    __syncthreads();
  }
  const float inv = 1.f / red[0];
#pragma unroll
  for (int j = 0; j < 8; j++) S[(size_t)n * Nn + t + j * 256] = f2bf(v[j] * inv);
}

// ---------------------------------------------------------------------------
// K2: x[b,n,i] -> Xrow[n][w=b*64+i] (bf16) and XT[w][n] (bf16)
// ---------------------------------------------------------------------------
__global__ __launch_bounds__(256) void x2xt_kernel(
    const float* __restrict__ x, unsigned short* __restrict__ Xrow,
    unsigned short* __restrict__ XT) {
  __shared__ float T[64 * 65];
  const int b = blockIdx.x, n0 = blockIdx.y * 64, t = threadIdx.x;
  const int i4 = (t & 15) * 4;
#pragma unroll
  for (int j = 0; j < 4; j++) {
    const int r = j * 16 + (t >> 4);       // 0..63
    const float4 v =
        *(const float4*)(x + (size_t)b * (Nn * CI) + (size_t)(n0 + r) * CI + i4);
    us4 o; o.x = f2bf(v.x); o.y = f2bf(v.y); o.z = f2bf(v.z); o.w = f2bf(v.w);
    *(us4*)(Xrow + (size_t)(n0 + r) * NW + b * CI + i4) = o;
    T[r * 65 + i4 + 0] = v.x; T[r * 65 + i4 + 1] = v.y;
    T[r * 65 + i4 + 2] = v.z; T[r * 65 + i4 + 3] = v.w;
  }
  __syncthreads();
  const int i = t >> 2, c0 = (t & 3) * 16;
  us8 p0, p1;
#pragma unroll
  for (int j = 0; j < 8; j++) p0[j] = f2bf(T[(c0 + j) * 65 + i]);
#pragma unroll
  for (int j = 0; j < 8; j++) p1[j] = f2bf(T[(c0 + 8 + j) * 65 + i]);
  unsigned short* dst = XT + (size_t)(b * CI + i) * Nn + n0 + c0;
  *(us8*)(dst) = p0;
  *(us8*)(dst + 8) = p1;
}

// ---------------------------------------------------------------------------
// K3: MFMA GEMM (unchanged from R3 — verified)
// ---------------------------------------------------------------------------
__global__ __launch_bounds__(256) void mfma_gemm(
    const unsigned short* __restrict__ A, const unsigned short* __restrict__ Bt,
    const unsigned short* __restrict__ Xsub, unsigned short* __restrict__ Crow,
    unsigned short* __restrict__ Ct, int mode) {
  __shared__ unsigned short sm[16384];
  unsigned short* As = sm;
  unsigned short* Bs = sm + 8192;
  const int t = threadIdx.x, lane = t & 63, wave = t >> 6;
  const int n0 = blockIdx.x * 128, m0 = blockIdx.y * 128;
  const int wm = (wave & 1) * 64, wn = (wave >> 1) * 64;
  const int lr = lane & 15, lq = lane >> 4;

  f32x4 acc[4][4] = {};
  const int srow = lane >> 3;
  const int schunk = (lane & 7) ^ srow;

  for (int k0 = 0; k0 < 2048; k0 += 64) {
    __syncthreads();
#pragma unroll
    for (int j = 0; j < 4; j++) {
      const int r0 = (wave * 4 + j) * 8;
      gl2lds16(A  + (size_t)(m0 + r0 + srow) * 2048 + k0 + schunk * 8, As + r0 * 64);
      gl2lds16(Bt + (size_t)(n0 + r0 + srow) * 2048 + k0 + schunk * 8, Bs + r0 * 64);
    }
    __syncthreads();
#pragma unroll
    for (int ks = 0; ks < 2; ks++) {
      short8 af[4], bfr[4];
#pragma unroll
      for (int i = 0; i < 4; i++) {
        const int m = wm + i * 16 + lr;
        const int slot = (ks * 4 + lq) ^ (m & 7);
        af[i] = *(const short8*)(As + m * 64 + slot * 8);
      }
#pragma unroll
      for (int j = 0; j < 4; j++) {
        const int n = wn + j * 16 + lr;
        const int slot = (ks * 4 + lq) ^ (n & 7);
        bfr[j] = *(const short8*)(Bs + n * 64 + slot * 8);
      }
#pragma unroll
      for (int i = 0; i < 4; i++)
#pragma unroll
        for (int j = 0; j < 4; j++)
          acc[i][j] = __builtin_amdgcn_mfma_f32_16x16x32_bf16(af[i], bfr[j], acc[i][j], 0, 0, 0);
    }
  }

  __syncthreads();
#pragma unroll
  for (int i = 0; i < 4; i++) {
#pragma unroll
    for (int r = 0; r < 4; r++) {
      const int m = wm + i * 16 + lq * 4 + r;
      const int sw = (m & 7) ^ ((m >> 3) & 7);
#pragma unroll
      for (int j = 0; j < 4; j++) {
        const int n = wn + j * 16 + lr;
        sm[m * 128 + (((n >> 3) ^ sw) * 8) + (n & 7)] = f2bf(acc[i][j][r]);
      }
    }
  }
  __syncthreads();

  {
    const int rr = t >> 4, cc = (t & 15) * 8;
#pragma unroll
    for (int p = 0; p < 8; p++) {
      const int m = p * 16 + rr;
      const int slot = (cc >> 3) ^ (m & 7) ^ ((m >> 3) & 7);
      us8 v = *(const us8*)(sm + m * 128 + slot * 8);
      if (mode == 1) {
        const us8 xv = *(const us8*)(Xsub + (size_t)(m0 + m) * NW + n0 + cc);
#pragma unroll
        for (int q = 0; q < 8; q++) v[q] = f2bf(2.f * bf2f(v[q]) - bf2f(xv[q]));
      }
      *(us8*)(Crow + (size_t)(m0 + m) * NW + n0 + cc) = v;
    }
  }
  if (mode == 0) {
    const int w = t >> 4, mc = (t & 15) * 8;
#pragma unroll
    for (int p = 0; p < 8; p++) {
      const int n = p * 16 + w;
      us8 v;
#pragma unroll
      for (int q = 0; q < 8; q++) {
        const int m = mc + q;
        v[q] = sm[m * 128 + (((n >> 3) ^ (m & 7) ^ ((m >> 3) & 7)) * 8) + (n & 7)];
      }
      *(us8*)(Ct + (size_t)(n0 + n) * 2048 + m0 + mc) = v;
    }
  }
}

// ---------------------------------------------------------------------------
// K4 v2: per-node output projection via MFMA.
// One block = one node, 4 waves. M=batch=64, N=CO=64 (16 per wave), K=192.
//   Phase 1 (issued first): activations -> Al LDS via global_load_lds,
//           XOR-chunk swizzle identical to mfma_gemm (row = (c,b), 8 chunks).
//   Phase 2: W_n = sum_d e_d Wp[d] (float4 loads, fp32 acc) -> bf16 into
//           Wt[c][o][i] pitch 72 (B-operand rows, 16B-aligned b128 frags).
//   Phase 3: 24 MFMA 16x16x32 per wave; epilogue adds bias, fp32 store.
// ---------------------------------------------------------------------------
__global__ __launch_bounds__(256) void out_kernel(
    const unsigned short* __restrict__ Xrow, const unsigned short* __restrict__ XG1,
    const unsigned short* __restrict__ XG2, const float* __restrict__ E,
    const float* __restrict__ Wp, const float* __restrict__ bp,
    float* __restrict__ out) {
  constexpr int WP = 72;                      // Wt row pitch (us), 144 B
  __shared__ unsigned short Wt[KK * CO * WP]; // 27648 B
  __shared__ unsigned short Al[KK * Bb * CI]; // 24576 B: row r=(c*64+b), 64 us
  __shared__ float biasl[CO];

  const int n = blockIdx.x, t = threadIdx.x, lane = t & 63, wave = t >> 6;

  // --- Phase 1: issue activation staging DMA (overlaps weight gen) ---
  const unsigned short* srcs[KK] = {Xrow + (size_t)n * NW, XG1 + (size_t)n * NW,
                                    XG2 + (size_t)n * NW};
  const int srow = lane >> 3;             // 0..7
  const int schunk = (lane & 7) ^ srow;   // chunk fetched into slot lane&7
#pragma unroll
  for (int j = 0; j < 6; j++) {
    const int r0 = (wave * 6 + j) * 8;    // row group 0..184, rows=(c,b)
    const int c = r0 >> 6, b0 = r0 & 63;
    gl2lds16(srcs[c] + (b0 + srow) * 64 + schunk * 8, Al + r0 * 64);
  }

  // --- Phase 2: weight + bias generation ---
  float emb[DE];
#pragma unroll
  for (int d = 0; d < DE; d++) emb[d] = E[n * DE + d];

#pragma unroll
  for (int j = 0; j < 12; j++) {
    const int idx4 = j * 1024 + t * 4;            // Wp inner index (c,i,o)
    const int c = j >> 2;
    const int i = (j * 16 + (t >> 4)) & 63;
    const int o = (t & 15) * 4;
    f32x4 w = {0.f, 0.f, 0.f, 0.f};
#pragma unroll
    for (int d = 0; d < DE; d++) {
      const float4 wp = *(const float4*)(Wp + (size_t)d * WPSZ + idx4);
      w[0] += emb[d] * wp.x; w[1] += emb[d] * wp.y;
      w[2] += emb[d] * wp.z; w[3] += emb[d] * wp.w;
    }
#pragma unroll
    for (int q = 0; q < 4; q++)
      Wt[c * (CO * WP) + (o + q) * WP + i] = f2bf(w[q]);
  }
  if (t < CO) {
    float bsum = 0.f;
#pragma unroll
    for (int d = 0; d < DE; d++) bsum += emb[d] * bp[d * CO + t];
    biasl[t] = bsum;
  }
  __syncthreads();   // drains global_load_lds (vmcnt) + LDS writes

  // --- Phase 3: MFMA. wave's o-slice = wave*16 + lr ---
  const int lr = lane & 15, lq = lane >> 4;
  f32x4 acc[4] = {};
#pragma unroll
  for (int kt = 0; kt < 6; kt++) {
    const int c = kt >> 1;
    const int i0 = (kt & 1) * 32;
    const short8 bfrag = *(const short8*)(Wt + c * (CO * WP) +
                                          (wave * 16 + lr) * WP + i0 + lq * 8);
#pragma unroll
    for (int mt = 0; mt < 4; mt++) {
      const int b = mt * 16 + lr;
      const int chunk = (kt & 1) * 4 + lq;
      const int slot = chunk ^ (b & 7);
      const short8 afrag = *(const short8*)(Al + (c * 64 + b) * 64 + slot * 8);
      acc[mt] = __builtin_amdgcn_mfma_f32_16x16x32_bf16(afrag, bfrag, acc[mt], 0, 0, 0);
    }
  }

  const float bias_o = biasl[wave * 16 + lr];
#pragma unroll
  for (int mt = 0; mt < 4; mt++) {
#pragma unroll
    for (int r = 0; r < 4; r++) {
      const int b = mt * 16 + lq * 4 + r;
      out[(size_t)b * (Nn * CO) + (size_t)n * CO + wave * 16 + lr] =
          acc[mt][r] + bias_o;
    }
  }
}

// ---------------------------------------------------------------------------
extern "C" void kernel_launch(void* const* d_in, const int* in_sizes, int n_in,
                              void* d_out, int out_size, void* d_ws,
                              size_t ws_size, hipStream_t stream) {
  const float* x  = (const float*)d_in[0];
  const float* E  = (const float*)d_in[1];
  const float* Wp = (const float*)d_in[2];
  const float* bp = (const float*)d_in[3];
  float* out = (float*)d_out;

  unsigned short* S    = (unsigned short*)d_ws;          // [2048][2048]
  unsigned short* XT   = S    + (size_t)Nn * Nn;         // [4096][2048]
  unsigned short* Xrow = XT   + (size_t)NW * Nn;         // [2048][4096]
  unsigned short* XG1T = Xrow + (size_t)Nn * NW;         // [4096][2048]
  unsigned short* XG1r = XG1T + (size_t)NW * Nn;         // [2048][4096]
  unsigned short* XG2r = XG1r + (size_t)Nn * NW;         // [2048][4096]

  supports_kernel<<<Nn, 256, 0, stream>>>(E, S);
  x2xt_kernel<<<dim3(Bb, Nn / 64), 256, 0, stream>>>(x, Xrow, XT);

  dim3 g(NW / 128, Nn / 128);  // (32, 16)
  mfma_gemm<<<g, 256, 0, stream>>>(S, XT,   nullptr, XG1r, XG1T, 0);
  mfma_gemm<<<g, 256, 0, stream>>>(S, XG1T, Xrow,    XG2r, nullptr, 1);

  out_kernel<<<Nn, 256, 0, stream>>>(Xrow, XG1r, XG2r, E, Wp, bp, out);
}